// Round 1
// 357.465 us; speedup vs baseline: 1.0195x; 1.0195x over previous
//
#include <hip/hip_runtime.h>
#include <math.h>

#define W 4096
#define S 4096
#define NK_MAX 1024

typedef float v4f __attribute__((ext_vector_type(4)));  // clang vector — valid for nontemporal builtins

// ---------------------------------------------------------------------------
// ws layout (floats):
//   [0,     8192)  : key table float2[4096]  (cos,sin) of 2*pi*k/4096
//   [8192, 16384)  : nm    float2[4096]  (noisy_mix, interleaved re/im)
//   [16384,17408)  : corr  float[1024]
//   [17408,25600)  : ck    float2[4096]  (clean_key)
// ---------------------------------------------------------------------------

// Stage 0: exact key table (fp64 sincos of small phases -> no range-reduction
// error). nm is now written directly by nm_kernel (no atomics), so no zeroing.
__global__ void prep_kernel(float2* __restrict__ table) {
    int k = blockIdx.x * blockDim.x + threadIdx.x;
    if (k >= W) return;
    double theta = (double)k * (6.283185307179586 / (double)W);
    table[k] = make_float2((float)cos(theta), (float)sin(theta));
}

// Stage 1: noisy_mix[w] = sum_s holo[w,s]*conj(cue[w,s]).
// One block per row: 256 threads x 4 float4 per array = 16 independent 16B
// loads in flight per thread (vs 4 before) -> latency-hiding via ILP, and the
// row sum completes in ONE block: no atomics, no cross-XCD ping-pong, direct
// store. cue is single-use -> nontemporal loads keep holo L3-resident for
// out_kernel's second read.
__global__ void nm_kernel(const float* __restrict__ hr, const float* __restrict__ hi,
                          const float* __restrict__ cr, const float* __restrict__ ci,
                          float2* __restrict__ nm) {
    int w = blockIdx.x;
    int t = threadIdx.x;
    size_t base = (size_t)w * 1024;  // 1024 float4 per row
    const v4f* hr4 = (const v4f*)hr;
    const v4f* hi4 = (const v4f*)hi;
    const v4f* cr4 = (const v4f*)cr;
    const v4f* ci4 = (const v4f*)ci;

    v4f a[4], b[4], c[4], d[4];
#pragma unroll
    for (int k = 0; k < 4; k++) {
        size_t i = base + t + k * 256;
        a[k] = hr4[i];
        b[k] = hi4[i];
        c[k] = __builtin_nontemporal_load(&cr4[i]);
        d[k] = __builtin_nontemporal_load(&ci4[i]);
    }
    // (hr + i*hi)(cr - i*ci): re = hr*cr + hi*ci ; im = hi*cr - hr*ci
    v4f vr = {0.f, 0.f, 0.f, 0.f}, vi = {0.f, 0.f, 0.f, 0.f};
#pragma unroll
    for (int k = 0; k < 4; k++) {
        vr += a[k] * c[k] + b[k] * d[k];
        vi += b[k] * c[k] - a[k] * d[k];
    }
    float sr = vr.x + vr.y + vr.z + vr.w;
    float si = vi.x + vi.y + vi.z + vi.w;

    for (int off = 32; off; off >>= 1) {
        sr += __shfl_down(sr, off);
        si += __shfl_down(si, off);
    }
    __shared__ float s0[4], s1[4];
    int lane = t & 63, wid = t >> 6;
    if (lane == 0) { s0[wid] = sr; s1[wid] = si; }
    __syncthreads();
    if (t == 0) {
        nm[w] = make_float2(s0[0] + s0[1] + s0[2] + s0[3],
                            s1[0] + s1[1] + s1[2] + s1[3]);
    }
}

// Stage 2: correlations[n] = |sum_w keys[n,w]*noisy_mix[w]| (no conjugation).
// One block per key; table/nm are L1/L2-hot (32 KB each).
__global__ void corr_kernel(const float2* __restrict__ nm, const float2* __restrict__ table,
                            float* __restrict__ corr, const int* __restrict__ nkp) {
    int n = blockIdx.x;
    if (n >= *nkp) return;
    int f = n + 1;
    float sr = 0.f, si = 0.f;
    for (int w = threadIdx.x; w < W; w += 256) {
        int idx = (w * f) & (W - 1);
        float2 t = table[idx];
        float2 v = nm[w];
        sr += t.x * v.x - t.y * v.y;
        si += t.x * v.y + t.y * v.x;
    }
    for (int off = 32; off; off >>= 1) {
        sr += __shfl_down(sr, off);
        si += __shfl_down(si, off);
    }
    __shared__ float s0[4], s1[4];
    int lane = threadIdx.x & 63, wid = threadIdx.x >> 6;
    if (lane == 0) { s0[wid] = sr; s1[wid] = si; }
    __syncthreads();
    if (threadIdx.x == 0) {
        float r = s0[0] + s0[1] + s0[2] + s0[3];
        float m = s1[0] + s1[1] + s1[2] + s1[3];
        corr[n] = sqrtf(r * r + m * m);
    }
}

// Stage 3+4 fused: each block recomputes softmax(corr*50) (deterministic,
// identical in every block), then computes clean_key for 64 rows with the
// key table staged in LDS. 4 threads per row, 256 keys each, shuffle-combine.
__global__ void ck_kernel(const float* __restrict__ corr, const float2* __restrict__ table,
                          float2* __restrict__ ck, const int* __restrict__ nkp) {
    __shared__ float2 stab[W];       // 32 KB
    __shared__ float satt[NK_MAX];   // 4 KB
    __shared__ float red[8];
    int t = threadIdx.x;
    int nk = *nkp;
    int lane = t & 63, wid = t >> 6;

    for (int i = t; i < W; i += 256) stab[i] = table[i];

    // --- block softmax over corr[0..nk) ---
    float v[4];
    float vmax = -INFINITY;
    for (int j = 0; j < 4; j++) {
        int i = t + j * 256;
        v[j] = (i < nk) ? corr[i] * 50.0f : -INFINITY;
        vmax = fmaxf(vmax, v[j]);
    }
    for (int off = 32; off; off >>= 1) vmax = fmaxf(vmax, __shfl_down(vmax, off));
    if (lane == 0) red[wid] = vmax;
    __syncthreads();
    float M = fmaxf(fmaxf(red[0], red[1]), fmaxf(red[2], red[3]));
    __syncthreads();

    float esum = 0.f;
    for (int j = 0; j < 4; j++) {
        int i = t + j * 256;
        float e = (i < nk) ? expf(v[j] - M) : 0.f;
        if (i < NK_MAX) satt[i] = e;
        esum += e;
    }
    for (int off = 32; off; off >>= 1) esum += __shfl_down(esum, off);
    if (lane == 0) red[4 + wid] = esum;
    __syncthreads();
    float SUM = red[4] + red[5] + red[6] + red[7];
    // satt holds unnormalized exp; divide by SUM at the end (linear op).

    // --- clean_key: 64 rows per block, 4 threads per row ---
    int wl = t >> 2, sub = t & 3;
    int w = blockIdx.x * 64 + wl;
    int n0 = sub * 256;
    float crr = 0.f, cii = 0.f;
    int idx = (int)(((long long)w * (n0 + 1)) & (W - 1));
    int nend = min(n0 + 256, nk);
    for (int n = n0; n < nend; n++) {
        float2 tt = stab[idx];
        float a = satt[n];
        crr += a * tt.x;
        cii += a * tt.y;
        idx = (idx + w) & (W - 1);
    }
    // combine the 4 sub-partials (lanes t^1, t^2 are in the same wave)
    crr += __shfl_xor(crr, 1); cii += __shfl_xor(cii, 1);
    crr += __shfl_xor(crr, 2); cii += __shfl_xor(cii, 2);
    if (sub == 0 && w < W) ck[w] = make_float2(crr / SUM, cii / SUM);
}

// Stage 5: out[0,w,s] = hr*ckr - hi*cki ; out[1,w,s] = hr*cki + hi*ckr.
// One block per row, 4 float4 per array per thread (same ILP fix as nm).
// w = blockIdx.x is provably wave-uniform -> ck[w] compiles to a scalar load.
// NT stores: output is written once, never re-read on device — keep it out
// of LLC so holo stays resident for the next replay.
__global__ void out_kernel(const float* __restrict__ hr, const float* __restrict__ hi,
                           const float2* __restrict__ ck, float* __restrict__ out) {
    int w = blockIdx.x;
    int t = threadIdx.x;
    size_t base = (size_t)w * 1024;  // 1024 float4 per row
    const size_t total4 = (size_t)W * S / 4;
    float2 c = ck[w];

    v4f a[4], b[4];
#pragma unroll
    for (int k = 0; k < 4; k++) {
        size_t i = base + t + k * 256;
        a[k] = ((const v4f*)hr)[i];
        b[k] = ((const v4f*)hi)[i];
    }
#pragma unroll
    for (int k = 0; k < 4; k++) {
        size_t i = base + t + k * 256;
        v4f re = a[k] * c.x - b[k] * c.y;
        v4f im = a[k] * c.y + b[k] * c.x;
        __builtin_nontemporal_store(re, &((v4f*)out)[i]);
        __builtin_nontemporal_store(im, &((v4f*)out)[i + total4]);
    }
}

extern "C" void kernel_launch(void* const* d_in, const int* in_sizes, int n_in,
                              void* d_out, int out_size, void* d_ws, size_t ws_size,
                              hipStream_t stream) {
    const float* hr = (const float*)d_in[0];
    const float* hi = (const float*)d_in[1];
    const float* cr = (const float*)d_in[2];
    const float* ci = (const float*)d_in[3];
    const int* nk = (const int*)d_in[4];

    float* ws = (float*)d_ws;
    float2* table = (float2*)ws;            // [0, 8192)
    float2* nm    = (float2*)(ws + 8192);   // [8192, 16384)
    float* corr   = ws + 16384;             // [16384, 17408)
    float2* ck    = (float2*)(ws + 17408);  // [17408, 25600)
    float* out = (float*)d_out;

    prep_kernel<<<W / 256, 256, 0, stream>>>(table);
    nm_kernel<<<W, 256, 0, stream>>>(hr, hi, cr, ci, nm);
    corr_kernel<<<NK_MAX, 256, 0, stream>>>(nm, table, corr, nk);
    ck_kernel<<<W / 64, 256, 0, stream>>>(corr, table, ck, nk);
    out_kernel<<<W, 256, 0, stream>>>(hr, hi, ck, out);
}

// Round 2
// 336.957 us; speedup vs baseline: 1.0816x; 1.0609x over previous
//
#include <hip/hip_runtime.h>
#include <math.h>

#define W 4096
#define S 4096
#define NK_MAX 1024

typedef float v4f __attribute__((ext_vector_type(4)));  // clang vector — valid for nontemporal builtins

// ---------------------------------------------------------------------------
// ws layout (floats):
//   [0,     8192)  : key table float2[4096]  (cos,sin) of 2*pi*k/4096
//   [8192, 16384)  : nm    float2[4096]  (noisy_mix, interleaved re/im)
//   [16384,17408)  : corr  float[1024]
// ---------------------------------------------------------------------------
// Chain is 3 kernels (was 5): nm(+table prep) -> corr -> out(+clean_key).
// ---------------------------------------------------------------------------

// Stage 0+1 fused: noisy_mix[w] = sum_s holo[w,s]*conj(cue[w,s]), and thread 0
// of block w computes table[w] (fp64 sincos of small phase -> exact) while the
// row loads are in flight. One block per row: 256 threads x 4 float4 per array
// = 16 independent 16B loads in flight per thread; row sum completes in ONE
// block: no atomics, direct store. cue is single-use -> nontemporal loads keep
// holo L3-resident for out_kernel's second read.
__global__ void nm_kernel(const float* __restrict__ hr, const float* __restrict__ hi,
                          const float* __restrict__ cr, const float* __restrict__ ci,
                          float2* __restrict__ nm, float2* __restrict__ table) {
    int w = blockIdx.x;
    int t = threadIdx.x;
    size_t base = (size_t)w * 1024;  // 1024 float4 per row
    const v4f* hr4 = (const v4f*)hr;
    const v4f* hi4 = (const v4f*)hi;
    const v4f* cr4 = (const v4f*)cr;
    const v4f* ci4 = (const v4f*)ci;

    v4f a[4], b[4], c[4], d[4];
#pragma unroll
    for (int k = 0; k < 4; k++) {
        size_t i = base + t + k * 256;
        a[k] = hr4[i];
        b[k] = hi4[i];
        c[k] = __builtin_nontemporal_load(&cr4[i]);
        d[k] = __builtin_nontemporal_load(&ci4[i]);
    }

    // table prep hidden under the load latency above
    if (t == 0) {
        double theta = (double)w * (6.283185307179586 / (double)W);
        table[w] = make_float2((float)cos(theta), (float)sin(theta));
    }

    // (hr + i*hi)(cr - i*ci): re = hr*cr + hi*ci ; im = hi*cr - hr*ci
    v4f vr = {0.f, 0.f, 0.f, 0.f}, vi = {0.f, 0.f, 0.f, 0.f};
#pragma unroll
    for (int k = 0; k < 4; k++) {
        vr += a[k] * c[k] + b[k] * d[k];
        vi += b[k] * c[k] - a[k] * d[k];
    }
    float sr = vr.x + vr.y + vr.z + vr.w;
    float si = vi.x + vi.y + vi.z + vi.w;

    for (int off = 32; off; off >>= 1) {
        sr += __shfl_down(sr, off);
        si += __shfl_down(si, off);
    }
    __shared__ float s0[4], s1[4];
    int lane = t & 63, wid = t >> 6;
    if (lane == 0) { s0[wid] = sr; s1[wid] = si; }
    __syncthreads();
    if (t == 0) {
        nm[w] = make_float2(s0[0] + s0[1] + s0[2] + s0[3],
                            s1[0] + s1[1] + s1[2] + s1[3]);
    }
}

// Stage 2: correlations[n] = |sum_w keys[n,w]*noisy_mix[w]| (no conjugation).
// One block per key; table/nm are L1/L2-hot (32 KB each).
__global__ void corr_kernel(const float2* __restrict__ nm, const float2* __restrict__ table,
                            float* __restrict__ corr, const int* __restrict__ nkp) {
    int n = blockIdx.x;
    if (n >= *nkp) return;
    int f = n + 1;
    float sr = 0.f, si = 0.f;
    for (int w = threadIdx.x; w < W; w += 256) {
        int idx = (w * f) & (W - 1);
        float2 t = table[idx];
        float2 v = nm[w];
        sr += t.x * v.x - t.y * v.y;
        si += t.x * v.y + t.y * v.x;
    }
    for (int off = 32; off; off >>= 1) {
        sr += __shfl_down(sr, off);
        si += __shfl_down(si, off);
    }
    __shared__ float s0[4], s1[4];
    int lane = threadIdx.x & 63, wid = threadIdx.x >> 6;
    if (lane == 0) { s0[wid] = sr; s1[wid] = si; }
    __syncthreads();
    if (threadIdx.x == 0) {
        float r = s0[0] + s0[1] + s0[2] + s0[3];
        float m = s1[0] + s1[1] + s1[2] + s1[3];
        corr[n] = sqrtf(r * r + m * m);
    }
}

// Stage 3+4+5 fused: one block per row. The block issues its 32 KB row loads
// FIRST, then (while they're in flight) recomputes softmax(corr*50)
// (deterministic, identical in every block, ~4 KB L2-hot reads) and its OWN
// row's clean_key: ck_w = sum_n att[n] * table[(w*(n+1)) & 4095]. That's 4
// keys/thread + two block reduces — entirely hidden under HBM latency.
// Then out[0,w,s] = hr*ckr - hi*cki ; out[1,w,s] = hr*cki + hi*ckr.
// NT stores: output is written once, never re-read on device.
__global__ void out_kernel(const float* __restrict__ hr, const float* __restrict__ hi,
                           const float* __restrict__ corr, const float2* __restrict__ table,
                           const int* __restrict__ nkp, float* __restrict__ out) {
    int w = blockIdx.x;
    int t = threadIdx.x;
    size_t base = (size_t)w * 1024;  // 1024 float4 per row
    const size_t total4 = (size_t)W * S / 4;
    int lane = t & 63, wid = t >> 6;
    __shared__ float red[8];

    // issue the row's streaming loads before any compute
    v4f a[4], b[4];
#pragma unroll
    for (int k = 0; k < 4; k++) {
        size_t i = base + t + k * 256;
        a[k] = ((const v4f*)hr)[i];
        b[k] = ((const v4f*)hi)[i];
    }

    int nk = *nkp;

    // --- block softmax over corr[0..nk) ---
    float v[4];
    float vmax = -INFINITY;
#pragma unroll
    for (int j = 0; j < 4; j++) {
        int i = t + j * 256;
        v[j] = (i < nk) ? corr[i] * 50.0f : -INFINITY;
        vmax = fmaxf(vmax, v[j]);
    }
    for (int off = 32; off; off >>= 1) vmax = fmaxf(vmax, __shfl_down(vmax, off));
    if (lane == 0) red[wid] = vmax;
    __syncthreads();
    float M = fmaxf(fmaxf(red[0], red[1]), fmaxf(red[2], red[3]));

    float e[4];
    float esum = 0.f;
#pragma unroll
    for (int j = 0; j < 4; j++) {
        int i = t + j * 256;
        e[j] = (i < nk) ? expf(v[j] - M) : 0.f;
        esum += e[j];
    }
    for (int off = 32; off; off >>= 1) esum += __shfl_down(esum, off);
    if (lane == 0) red[4 + wid] = esum;
    __syncthreads();
    float SUM = red[4] + red[5] + red[6] + red[7];
    __syncthreads();  // red about to be reused

    // --- this row's clean_key: 4 keys per thread, table reads L1/L2-hot ---
    float crr = 0.f, cii = 0.f;
#pragma unroll
    for (int j = 0; j < 4; j++) {
        int i = t + j * 256;
        if (i < nk) {
            int idx = (w * (i + 1)) & (W - 1);
            float2 tt = table[idx];
            crr += e[j] * tt.x;
            cii += e[j] * tt.y;
        }
    }
    for (int off = 32; off; off >>= 1) {
        crr += __shfl_down(crr, off);
        cii += __shfl_down(cii, off);
    }
    if (lane == 0) { red[wid] = crr; red[4 + wid] = cii; }
    __syncthreads();
    float ckr = (red[0] + red[1] + red[2] + red[3]) / SUM;
    float cki = (red[4] + red[5] + red[6] + red[7]) / SUM;

    // --- stream the row ---
#pragma unroll
    for (int k = 0; k < 4; k++) {
        size_t i = base + t + k * 256;
        v4f re = a[k] * ckr - b[k] * cki;
        v4f im = a[k] * cki + b[k] * ckr;
        __builtin_nontemporal_store(re, &((v4f*)out)[i]);
        __builtin_nontemporal_store(im, &((v4f*)out)[i + total4]);
    }
}

extern "C" void kernel_launch(void* const* d_in, const int* in_sizes, int n_in,
                              void* d_out, int out_size, void* d_ws, size_t ws_size,
                              hipStream_t stream) {
    const float* hr = (const float*)d_in[0];
    const float* hi = (const float*)d_in[1];
    const float* cr = (const float*)d_in[2];
    const float* ci = (const float*)d_in[3];
    const int* nk = (const int*)d_in[4];

    float* ws = (float*)d_ws;
    float2* table = (float2*)ws;            // [0, 8192)
    float2* nm    = (float2*)(ws + 8192);   // [8192, 16384)
    float* corr   = ws + 16384;             // [16384, 17408)
    float* out = (float*)d_out;

    nm_kernel<<<W, 256, 0, stream>>>(hr, hi, cr, ci, nm, table);
    corr_kernel<<<NK_MAX, 256, 0, stream>>>(nm, table, corr, nk);
    out_kernel<<<W, 256, 0, stream>>>(hr, hi, corr, table, nk, out);
}